// Round 4
// baseline (138.912 us; speedup 1.0000x reference)
//
#include <hip/hip_runtime.h>

typedef __attribute__((ext_vector_type(8))) __bf16 bf16x8;
typedef __attribute__((ext_vector_type(4))) float f32x4;
typedef _Float16 hf2 __attribute__((ext_vector_type(2)));
typedef _Float16 hf8 __attribute__((ext_vector_type(8)));
typedef unsigned short u16;
typedef struct { hf2 v[4]; } hf2x4;   // register-friendly view of hf8

__device__ __forceinline__ float bf2f(u16 h) {
    return __uint_as_float(((unsigned int)h) << 16);
}
__device__ __forceinline__ u16 f2bf(float f) {
    unsigned int u = __float_as_uint(f);
    u += 0x7fffu + ((u >> 16) & 1u);   // RNE
    return (u16)(u >> 16);
}

#if __has_builtin(__builtin_amdgcn_fdot2)
__device__ __forceinline__ float FDOT2(hf2 a, hf2 b, float c) {
    return __builtin_amdgcn_fdot2(a, b, c, false);
}
#else
__device__ __forceinline__ float FDOT2(hf2 a, hf2 b, float c) {
    return c + (float)a[0] + (float)a[1];   // b is all-ones in our use
}
#endif

#define GLOAD_LDS16(gsrc, ldst)                                                          \
    __builtin_amdgcn_global_load_lds(                                                    \
        (__attribute__((address_space(1))) unsigned int*)(gsrc),                         \
        (__attribute__((address_space(3))) unsigned int*)(ldst), 16, 0, 0)

// ---------------------------------------------------------------------------
// Fused f32 -> bf16/f16 convert with zero-padding to (Npad, Kpad)
// ---------------------------------------------------------------------------
struct CvtDesc { const float* src; u16* dst; int N, K, Npad, Kpad, blk0, fmt; };
struct CvtTab { CvtDesc t[11]; };

__global__ __launch_bounds__(256) void cvt_all(CvtTab tab) {
    int b = blockIdx.x;
    int ti = 0;
#pragma unroll
    for (int j = 1; j < 11; ++j)
        if (b >= tab.t[j].blk0) ti = j;
    const CvtDesc c = tab.t[ti];
    long i = (long)(b - c.blk0) * 256 + threadIdx.x;
    long tot = (long)c.Npad * c.Kpad;
    if (i >= tot) return;
    int n = (int)(i / c.Kpad);
    int k = (int)(i - (long)n * c.Kpad);
    float v = (n < c.N && k < c.K) ? c.src[(long)n * c.K + k] : 0.f;
    if (c.fmt) {
        _Float16 h = (_Float16)v;
        c.dst[i] = __builtin_bit_cast(u16, h);
    } else {
        c.dst[i] = f2bf(v);
    }
}

// ---------------------------------------------------------------------------
// bf16 MFMA GEMM body: out[m][n] = epi( sum_k A[m][k]*W[n][k] + bias[n] )
// BM=BN=BK=64, 256 threads (4 waves as 2x2), 16x16x32 MFMA.
// LDS tiles [64][64] bf16, XOR-swizzled granules via pre-swizzled global
// source + linear global_load_lds dest (rule 21).
// MODE: 0 = bf16 out (+opt res add), 1 = f32 out + addF, 2 = f16 out + addF
// ---------------------------------------------------------------------------
template<int RELU, int HASRES, int MODE>
__device__ __forceinline__ void gemm_body(
    char* lds,
    const u16* __restrict__ A, int lda,
    const u16* __restrict__ W, int ldw,
    const float* __restrict__ bias, int Nreal,
    u16* __restrict__ outB, int ldo,
    const u16* __restrict__ res,
    float* __restrict__ outF, _Float16* __restrict__ outH,
    const float* __restrict__ addF,
    int nk, int mb, int nb)
{
    char* ldsA = lds;
    char* ldsB = lds + 8192;

    const int tid  = threadIdx.x;
    const int wave = tid >> 6;
    const int lane = tid & 63;
    const int wr = wave >> 1, wc = wave & 1;
    const int lr = lane & 15, lk = lane >> 4;

    f32x4 acc[2][2];
#pragma unroll
    for (int i = 0; i < 2; ++i)
#pragma unroll
        for (int j = 0; j < 2; ++j)
#pragma unroll
            for (int e = 0; e < 4; ++e) acc[i][j][e] = 0.f;

    // staging granule geometry (8KB tile = 512 granules of 16B; 2 per thread)
    const int g0 = wave * 64 + lane;
    const int r0 = g0 >> 3, l0 = (g0 & 7) ^ (r0 & 7);
    const int g1 = g0 + 256;
    const int r1 = g1 >> 3, l1 = (g1 & 7) ^ (r1 & 7);

    for (int kt = 0; kt < nk; ++kt) {
        const int kk = kt * 64;
        GLOAD_LDS16(A + (size_t)(mb + r0) * lda + kk + l0 * 8, ldsA + wave * 1024);
        GLOAD_LDS16(A + (size_t)(mb + r1) * lda + kk + l1 * 8, ldsA + 4096 + wave * 1024);
        GLOAD_LDS16(W + (size_t)(nb + r0) * ldw + kk + l0 * 8, ldsB + wave * 1024);
        GLOAD_LDS16(W + (size_t)(nb + r1) * ldw + kk + l1 * 8, ldsB + 4096 + wave * 1024);
        __syncthreads();   // compiler drains vmcnt(0) before barrier
#pragma unroll
        for (int ks = 0; ks < 2; ++ks) {
            bf16x8 af[2], bfr[2];
#pragma unroll
            for (int mi = 0; mi < 2; ++mi) {
                int m_loc = wr * 32 + mi * 16 + lr;
                int gr = (ks * 4 + lk) ^ (m_loc & 7);
                af[mi] = *(const bf16x8*)(ldsA + m_loc * 128 + gr * 16);
            }
#pragma unroll
            for (int ni = 0; ni < 2; ++ni) {
                int n_loc = wc * 32 + ni * 16 + lr;
                int gr = (ks * 4 + lk) ^ (n_loc & 7);
                bfr[ni] = *(const bf16x8*)(ldsB + n_loc * 128 + gr * 16);
            }
#pragma unroll
            for (int mi = 0; mi < 2; ++mi)
#pragma unroll
                for (int ni = 0; ni < 2; ++ni)
                    acc[mi][ni] = __builtin_amdgcn_mfma_f32_16x16x32_bf16(
                        af[mi], bfr[ni], acc[mi][ni], 0, 0, 0);
        }
        __syncthreads();
    }

    // epilogue: C/D layout col = lane&15, row = (lane>>4)*4 + reg (m89-verified)
#pragma unroll
    for (int mi = 0; mi < 2; ++mi) {
#pragma unroll
        for (int ni = 0; ni < 2; ++ni) {
            const int n_g = nb + wc * 32 + ni * 16 + lr;
            const float bv = (n_g < Nreal) ? bias[n_g] : 0.f;
#pragma unroll
            for (int r = 0; r < 4; ++r) {
                const int m_g = mb + wr * 32 + mi * 16 + lk * 4 + r;
                float v = acc[mi][ni][r] + bv;
                if (RELU) v = fmaxf(v, 0.f);
                if (HASRES) v += bf2f(res[(size_t)m_g * ldo + n_g]);
                if (MODE == 1) {
                    outF[(size_t)m_g * 768 + n_g] = v + addF[(size_t)m_g * 768 + n_g];
                } else if (MODE == 2) {
                    outH[(size_t)m_g * 768 + n_g] =
                        (_Float16)(v + addF[(size_t)m_g * 768 + n_g]);
                } else {
                    outB[(size_t)m_g * ldo + n_g] = f2bf(v);
                }
            }
        }
    }
}

template<int RELU, int HASRES, int MODE>
__global__ __launch_bounds__(256) void gemm_k(
    const u16* __restrict__ A, int lda,
    const u16* __restrict__ W, int ldw,
    const float* __restrict__ bias, int Nreal,
    u16* __restrict__ outB, int ldo,
    const u16* __restrict__ res,
    float* __restrict__ outF, _Float16* __restrict__ outH,
    const float* __restrict__ addF, int nk)
{
    __shared__ __align__(16) char lds[16384];
    gemm_body<RELU, HASRES, MODE>(lds, A, lda, W, ldw, bias, Nreal, outB, ldo,
                                  res, outF, outH, addF, nk,
                                  blockIdx.x * 64, blockIdx.y * 64);
}

// merged adapter (MODE 1, f32 out = v + x) and down0 (bf16 relu out): share A=xb
__global__ __launch_bounds__(256) void gemm_ad0(
    const u16* __restrict__ xb,
    const u16* __restrict__ aWb, const float* __restrict__ ab,
    float* __restrict__ adF, const float* __restrict__ x,
    const u16* __restrict__ Wd0b, const float* __restrict__ bd0,
    u16* __restrict__ h1)
{
    __shared__ __align__(16) char lds[16384];
    if (blockIdx.y < 12) {
        gemm_body<0, 0, 1>(lds, xb, 768, aWb, 768, ab, 768, nullptr, 0,
                           nullptr, adF, nullptr, x, 12,
                           blockIdx.x * 64, blockIdx.y * 64);
    } else {
        gemm_body<1, 0, 0>(lds, xb, 768, Wd0b, 768, bd0, 384, h1, 384,
                           nullptr, nullptr, nullptr, nullptr, 12,
                           blockIdx.x * 64, (blockIdx.y - 12) * 64);
    }
}

// ---------------------------------------------------------------------------
// L1 head v3: out[b][p] = -sum_d |feat[b][d] - protos[p][d]|  (f16 in, f32 acc)
// Grid (16 row-blocks, 4 proto-blocks, 12 d-chunks), 256 thr, 1 chunk/block.
// Block: 128 rows x 64 protos x 64 d. Thread: 8 rows (tr+16i) x 4 protos.
// Inner: packed-f16 sub + bitwise abs + v_dot2_f32_f16 into f32 acc
// (3 VALU per 2 d per cell). LDS: fs[128][64] f16 + pt[32][64] hf2 = 24KB.
// Reads broadcast (16 lanes same addr), writes diagonal -> conflict-free.
// ---------------------------------------------------------------------------
__global__ __launch_bounds__(256) void l1_kernel(
    const _Float16* __restrict__ feat, const _Float16* __restrict__ protos,
    float* __restrict__ out)
{
    __shared__ _Float16 fs[128][64];
    __shared__ hf2 pt[32][64];        // [d-pair][proto]
    const int tid = threadIdx.x;
    const int tp = tid & 15, tr = tid >> 4;
    const int rb = blockIdx.x * 128;
    const int pb = blockIdx.y * 64;
    const int db = blockIdx.z * 64;

    // stage fs: thread -> (row r0+32k, granule g), 4 x b128, coalesced
    {
        const int g = tid & 7, r0 = tid >> 3;
#pragma unroll
        for (int k = 0; k < 4; ++k) {
            const int r = r0 + 32 * k;
            *(hf8*)&fs[r][g * 8] =
                *(const hf8*)&feat[(size_t)(rb + r) * 768 + db + g * 8];
        }
    }
    // stage pt (transposed pairs): thread owns proto sp, d-pairs q*8..q*8+7
    {
        const int sp = tid & 63, q = tid >> 6;
        const _Float16* src = &protos[(size_t)(pb + sp) * 768 + db + q * 16];
        hf8 v0 = *(const hf8*)src;
        hf8 v1 = *(const hf8*)(src + 8);
        hf2x4 w0 = __builtin_bit_cast(hf2x4, v0);
        hf2x4 w1 = __builtin_bit_cast(hf2x4, v1);
#pragma unroll
        for (int e = 0; e < 4; ++e)
            pt[q * 8 + e][sp] = w0.v[e];
#pragma unroll
        for (int e = 0; e < 4; ++e)
            pt[q * 8 + 4 + e][sp] = w1.v[e];
    }
    __syncthreads();

    float acc[8][4];
#pragma unroll
    for (int i = 0; i < 8; ++i)
#pragma unroll
        for (int j = 0; j < 4; ++j) acc[i][j] = 0.f;

    const hf2 one2 = {(_Float16)1.0f, (_Float16)1.0f};
#pragma unroll 2
    for (int g = 0; g < 8; ++g) {
        hf2x4 F2[8];
#pragma unroll
        for (int i = 0; i < 8; ++i)
            F2[i] = __builtin_bit_cast(hf2x4,
                        *(const hf8*)&fs[tr + 16 * i][g * 8]);
        hf2x4 P2[4];
#pragma unroll
        for (int q = 0; q < 4; ++q)
            P2[q] = __builtin_bit_cast(hf2x4,
                        *(const hf8*)&pt[g * 4 + q][tp * 4]);
#pragma unroll
        for (int q = 0; q < 4; ++q) {
#pragma unroll
            for (int j = 0; j < 4; ++j) {
                const hf2 pj = P2[q].v[j];
#pragma unroll
                for (int i = 0; i < 8; ++i) {
                    hf2 d = F2[i].v[q] - pj;
                    unsigned ud = __builtin_bit_cast(unsigned, d) & 0x7FFF7FFFu;
                    acc[i][j] = FDOT2(__builtin_bit_cast(hf2, ud), one2, acc[i][j]);
                }
            }
        }
    }
#pragma unroll
    for (int j = 0; j < 4; ++j) {
        const int p = pb + tp * 4 + j;
        if (p < 200) {
#pragma unroll
            for (int i = 0; i < 8; ++i)
                atomicAdd(&out[(size_t)(rb + tr + 16 * i) * 200 + p], -acc[i][j]);
        }
    }
}

// ---------------------------------------------------------------------------
// Workspace layout (bytes). Total ~21.8 MB.
// ---------------------------------------------------------------------------
static constexpr size_t OFF_XB    = 0;          // 2048x768 bf16
static constexpr size_t OFF_AWB   = 3145728;    // 768x768 bf16
static constexpr size_t OFF_WD0   = 4325376;    // 384x768
static constexpr size_t OFF_WD1   = 4915200;    // 192x384
static constexpr size_t OFF_WD2   = 5062656;    // 128x192
static constexpr size_t OFF_WD3   = 5111808;    // 64x128
static constexpr size_t OFF_WU0   = 5128192;    // 128x64
static constexpr size_t OFF_WU1   = 5144576;    // 192x128
static constexpr size_t OFF_WU2   = 5193728;    // 384x192
static constexpr size_t OFF_WU3   = 5341184;    // 768x384
static constexpr size_t OFF_H1    = 5931008;    // 2048x384 bf16
static constexpr size_t OFF_H2    = 7503872;    // 2048x192
static constexpr size_t OFF_H3    = 8290304;    // 2048x128
static constexpr size_t OFF_H4    = 8814592;    // 2048x64
static constexpr size_t OFF_U0    = 9076736;    // 2048x128
static constexpr size_t OFF_U1    = 9601024;    // 2048x192
static constexpr size_t OFF_U2    = 10387456;   // 2048x384
static constexpr size_t OFF_ADF   = 11960320;   // 2048x768 f32: x + x@aW.T + ab
static constexpr size_t OFF_FEATH = 18251776;   // 2048x768 f16: features
static constexpr size_t OFF_PROH  = 21397504;   // 256x768 f16: protos (padded)

extern "C" void kernel_launch(void* const* d_in, const int* in_sizes, int n_in,
                              void* d_out, int out_size, void* d_ws, size_t ws_size,
                              hipStream_t stream) {
    const float* x      = (const float*)d_in[0];
    const float* aW     = (const float*)d_in[1];
    const float* ab     = (const float*)d_in[2];
    const float* protos = (const float*)d_in[3];
    const float* Wd[4]  = {(const float*)d_in[4], (const float*)d_in[6],
                           (const float*)d_in[8], (const float*)d_in[10]};
    const float* bd[4]  = {(const float*)d_in[5], (const float*)d_in[7],
                           (const float*)d_in[9], (const float*)d_in[11]};
    const float* Wu[4]  = {(const float*)d_in[12], (const float*)d_in[14],
                           (const float*)d_in[16], (const float*)d_in[18]};
    const float* bu[4]  = {(const float*)d_in[13], (const float*)d_in[15],
                           (const float*)d_in[17], (const float*)d_in[19]};
    float* out = (float*)d_out;
    char* ws = (char*)d_ws;

    u16* xb    = (u16*)(ws + OFF_XB);
    u16* aWb   = (u16*)(ws + OFF_AWB);
    u16* Wd0b  = (u16*)(ws + OFF_WD0);
    u16* Wd1b  = (u16*)(ws + OFF_WD1);
    u16* Wd2b  = (u16*)(ws + OFF_WD2);
    u16* Wd3b  = (u16*)(ws + OFF_WD3);
    u16* Wu0b  = (u16*)(ws + OFF_WU0);
    u16* Wu1b  = (u16*)(ws + OFF_WU1);
    u16* Wu2b  = (u16*)(ws + OFF_WU2);
    u16* Wu3b  = (u16*)(ws + OFF_WU3);
    u16* h1    = (u16*)(ws + OFF_H1);
    u16* h2    = (u16*)(ws + OFF_H2);
    u16* h3    = (u16*)(ws + OFF_H3);
    u16* h4    = (u16*)(ws + OFF_H4);
    u16* u0    = (u16*)(ws + OFF_U0);
    u16* u1    = (u16*)(ws + OFF_U1);
    u16* u2    = (u16*)(ws + OFF_U2);
    float* adF = (float*)(ws + OFF_ADF);
    _Float16* featH = (_Float16*)(ws + OFF_FEATH);
    _Float16* proH  = (_Float16*)(ws + OFF_PROH);

    // --- 1. convert/pad everything (bf16 for GEMM, f16 for L1) ---
    CvtTab tab;
    int blk = 0;
    auto set = [&](int i, const float* s, u16* d, int N, int K, int Np, int Kp,
                   int fmt) {
        tab.t[i] = {s, d, N, K, Np, Kp, blk, fmt};
        blk += (Np * Kp + 255) / 256;
    };
    set(0,  x,      xb,          2048, 768, 2048, 768, 0);
    set(1,  aW,     aWb,         768,  768, 768,  768, 0);
    set(2,  Wd[0],  Wd0b,        384,  768, 384,  768, 0);
    set(3,  Wd[1],  Wd1b,        192,  384, 192,  384, 0);
    set(4,  Wd[2],  Wd2b,        96,   192, 128,  192, 0);
    set(5,  Wd[3],  Wd3b,        48,   96,  64,   128, 0);
    set(6,  Wu[0],  Wu0b,        96,   48,  128,  64,  0);
    set(7,  Wu[1],  Wu1b,        192,  96,  192,  128, 0);
    set(8,  Wu[2],  Wu2b,        384,  192, 384,  192, 0);
    set(9,  Wu[3],  Wu3b,        768,  384, 768,  384, 0);
    set(10, protos, (u16*)proH,  200,  768, 256,  768, 1);
    cvt_all<<<blk, 256, 0, stream>>>(tab);

    // --- 2. GEMM chain ---
    // adapter (adF = x + x@aW.T + ab) merged with down0 (h1) — both read xb
    gemm_ad0<<<dim3(32, 18), 256, 0, stream>>>(xb, aWb, ab, adF, x, Wd0b, bd[0], h1);
    gemm_k<1,0,0><<<dim3(32,3), 256, 0, stream>>>(h1, 384, Wd1b, 384, bd[1], 192,
        h2, 192, nullptr, nullptr, nullptr, nullptr, 6);
    gemm_k<1,0,0><<<dim3(32,2), 256, 0, stream>>>(h2, 192, Wd2b, 192, bd[2], 96,
        h3, 128, nullptr, nullptr, nullptr, nullptr, 3);
    gemm_k<1,0,0><<<dim3(32,1), 256, 0, stream>>>(h3, 128, Wd3b, 128, bd[3], 48,
        h4, 64, nullptr, nullptr, nullptr, nullptr, 2);
    gemm_k<1,1,0><<<dim3(32,2), 256, 0, stream>>>(h4, 64, Wu0b, 64, bu[0], 96,
        u0, 128, h3, nullptr, nullptr, nullptr, 1);     // u0 = relu(.)+h3
    gemm_k<1,1,0><<<dim3(32,3), 256, 0, stream>>>(u0, 128, Wu1b, 128, bu[1], 192,
        u1, 192, h2, nullptr, nullptr, nullptr, 2);     // u1 = relu(.)+h2
    gemm_k<1,0,0><<<dim3(32,6), 256, 0, stream>>>(u1, 192, Wu2b, 192, bu[2], 384,
        u2, 384, nullptr, nullptr, nullptr, nullptr, 3);
    // u3: featH = (f16)(relu(u2@Wu3.T + bu3) + adF)
    gemm_k<1,0,2><<<dim3(32,12), 256, 0, stream>>>(u2, 384, Wu3b, 384, bu[3], 768,
        nullptr, 0, nullptr, nullptr, featH, adF, 6);

    // --- 3. L1 prototype head: zero out, then atomic partial sums ---
    (void)hipMemsetAsync(d_out, 0, (size_t)2048 * 200 * sizeof(float), stream);
    l1_kernel<<<dim3(16, 4, 12), 256, 0, stream>>>(featH, proH, out);
}

// Round 5
// 90.568 us; speedup vs baseline: 1.5338x; 1.5338x over previous
//
#include <hip/hip_runtime.h>

typedef __attribute__((ext_vector_type(8))) __bf16 bf16x8;
typedef __attribute__((ext_vector_type(4))) float f32x4;
typedef _Float16 hf2 __attribute__((ext_vector_type(2)));
typedef _Float16 hf8 __attribute__((ext_vector_type(8)));
typedef unsigned short u16;
typedef struct { hf2 v[4]; } hf2x4;   // register-friendly view of hf8

__device__ __forceinline__ float bf2f(u16 h) {
    return __uint_as_float(((unsigned int)h) << 16);
}
__device__ __forceinline__ u16 f2bf(float f) {
    unsigned int u = __float_as_uint(f);
    u += 0x7fffu + ((u >> 16) & 1u);   // RNE
    return (u16)(u >> 16);
}

#if __has_builtin(__builtin_amdgcn_fdot2)
__device__ __forceinline__ float FDOT2(hf2 a, hf2 b, float c) {
    return __builtin_amdgcn_fdot2(a, b, c, false);
}
#else
__device__ __forceinline__ float FDOT2(hf2 a, hf2 b, float c) {
    return c + (float)a[0] + (float)a[1];   // b is all-ones in our use
}
#endif

#define GLOAD_LDS16(gsrc, ldst)                                                          \
    __builtin_amdgcn_global_load_lds(                                                    \
        (__attribute__((address_space(1))) unsigned int*)(gsrc),                         \
        (__attribute__((address_space(3))) unsigned int*)(ldst), 16, 0, 0)

// ---------------------------------------------------------------------------
// Fused f32 -> bf16/f16 convert with zero-padding to (Npad, Kpad)
// ---------------------------------------------------------------------------
struct CvtDesc { const float* src; u16* dst; int N, K, Npad, Kpad, blk0, fmt; };
struct CvtTab { CvtDesc t[11]; };

__global__ __launch_bounds__(256) void cvt_all(CvtTab tab) {
    int b = blockIdx.x;
    int ti = 0;
#pragma unroll
    for (int j = 1; j < 11; ++j)
        if (b >= tab.t[j].blk0) ti = j;
    const CvtDesc c = tab.t[ti];
    long i = (long)(b - c.blk0) * 256 + threadIdx.x;
    long tot = (long)c.Npad * c.Kpad;
    if (i >= tot) return;
    int n = (int)(i / c.Kpad);
    int k = (int)(i - (long)n * c.Kpad);
    float v = (n < c.N && k < c.K) ? c.src[(long)n * c.K + k] : 0.f;
    if (c.fmt) {
        _Float16 h = (_Float16)v;
        c.dst[i] = __builtin_bit_cast(u16, h);
    } else {
        c.dst[i] = f2bf(v);
    }
}

// ---------------------------------------------------------------------------
// bf16 MFMA GEMM body: out[m][n] = epi( sum_k A[m][k]*W[n][k] + bias[n] )
// BM=BN=BK=64, 256 threads (4 waves as 2x2), 16x16x32 MFMA.
// LDS tiles [64][64] bf16, XOR-swizzled granules via pre-swizzled global
// source + linear global_load_lds dest (rule 21).
// MODE: 0 = bf16 out (+opt res add), 1 = f32 out + addF, 2 = f16 out + addF
// ---------------------------------------------------------------------------
template<int RELU, int HASRES, int MODE>
__device__ __forceinline__ void gemm_body(
    char* lds,
    const u16* __restrict__ A, int lda,
    const u16* __restrict__ W, int ldw,
    const float* __restrict__ bias, int Nreal,
    u16* __restrict__ outB, int ldo,
    const u16* __restrict__ res,
    float* __restrict__ outF, _Float16* __restrict__ outH,
    const float* __restrict__ addF,
    int nk, int mb, int nb)
{
    char* ldsA = lds;
    char* ldsB = lds + 8192;

    const int tid  = threadIdx.x;
    const int wave = tid >> 6;
    const int lane = tid & 63;
    const int wr = wave >> 1, wc = wave & 1;
    const int lr = lane & 15, lk = lane >> 4;

    f32x4 acc[2][2];
#pragma unroll
    for (int i = 0; i < 2; ++i)
#pragma unroll
        for (int j = 0; j < 2; ++j)
#pragma unroll
            for (int e = 0; e < 4; ++e) acc[i][j][e] = 0.f;

    // staging granule geometry (8KB tile = 512 granules of 16B; 2 per thread)
    const int g0 = wave * 64 + lane;
    const int r0 = g0 >> 3, l0 = (g0 & 7) ^ (r0 & 7);
    const int g1 = g0 + 256;
    const int r1 = g1 >> 3, l1 = (g1 & 7) ^ (r1 & 7);

    for (int kt = 0; kt < nk; ++kt) {
        const int kk = kt * 64;
        GLOAD_LDS16(A + (size_t)(mb + r0) * lda + kk + l0 * 8, ldsA + wave * 1024);
        GLOAD_LDS16(A + (size_t)(mb + r1) * lda + kk + l1 * 8, ldsA + 4096 + wave * 1024);
        GLOAD_LDS16(W + (size_t)(nb + r0) * ldw + kk + l0 * 8, ldsB + wave * 1024);
        GLOAD_LDS16(W + (size_t)(nb + r1) * ldw + kk + l1 * 8, ldsB + 4096 + wave * 1024);
        __syncthreads();   // compiler drains vmcnt(0) before barrier
#pragma unroll
        for (int ks = 0; ks < 2; ++ks) {
            bf16x8 af[2], bfr[2];
#pragma unroll
            for (int mi = 0; mi < 2; ++mi) {
                int m_loc = wr * 32 + mi * 16 + lr;
                int gr = (ks * 4 + lk) ^ (m_loc & 7);
                af[mi] = *(const bf16x8*)(ldsA + m_loc * 128 + gr * 16);
            }
#pragma unroll
            for (int ni = 0; ni < 2; ++ni) {
                int n_loc = wc * 32 + ni * 16 + lr;
                int gr = (ks * 4 + lk) ^ (n_loc & 7);
                bfr[ni] = *(const bf16x8*)(ldsB + n_loc * 128 + gr * 16);
            }
#pragma unroll
            for (int mi = 0; mi < 2; ++mi)
#pragma unroll
                for (int ni = 0; ni < 2; ++ni)
                    acc[mi][ni] = __builtin_amdgcn_mfma_f32_16x16x32_bf16(
                        af[mi], bfr[ni], acc[mi][ni], 0, 0, 0);
        }
        __syncthreads();
    }

    // epilogue: C/D layout col = lane&15, row = (lane>>4)*4 + reg (m89-verified)
#pragma unroll
    for (int mi = 0; mi < 2; ++mi) {
#pragma unroll
        for (int ni = 0; ni < 2; ++ni) {
            const int n_g = nb + wc * 32 + ni * 16 + lr;
            const float bv = (n_g < Nreal) ? bias[n_g] : 0.f;
#pragma unroll
            for (int r = 0; r < 4; ++r) {
                const int m_g = mb + wr * 32 + mi * 16 + lk * 4 + r;
                float v = acc[mi][ni][r] + bv;
                if (RELU) v = fmaxf(v, 0.f);
                if (HASRES) v += bf2f(res[(size_t)m_g * ldo + n_g]);
                if (MODE == 1) {
                    outF[(size_t)m_g * 768 + n_g] = v + addF[(size_t)m_g * 768 + n_g];
                } else if (MODE == 2) {
                    outH[(size_t)m_g * 768 + n_g] =
                        (_Float16)(v + addF[(size_t)m_g * 768 + n_g]);
                } else {
                    outB[(size_t)m_g * ldo + n_g] = f2bf(v);
                }
            }
        }
    }
}

template<int RELU, int HASRES, int MODE>
__global__ __launch_bounds__(256) void gemm_k(
    const u16* __restrict__ A, int lda,
    const u16* __restrict__ W, int ldw,
    const float* __restrict__ bias, int Nreal,
    u16* __restrict__ outB, int ldo,
    const u16* __restrict__ res,
    float* __restrict__ outF, _Float16* __restrict__ outH,
    const float* __restrict__ addF, int nk)
{
    __shared__ __align__(16) char lds[16384];
    gemm_body<RELU, HASRES, MODE>(lds, A, lda, W, ldw, bias, Nreal, outB, ldo,
                                  res, outF, outH, addF, nk,
                                  blockIdx.x * 64, blockIdx.y * 64);
}

// merged adapter (MODE 1, f32 out = v + x) and down0 (bf16 relu out): share A=xb
__global__ __launch_bounds__(256) void gemm_ad0(
    const u16* __restrict__ xb,
    const u16* __restrict__ aWb, const float* __restrict__ ab,
    float* __restrict__ adF, const float* __restrict__ x,
    const u16* __restrict__ Wd0b, const float* __restrict__ bd0,
    u16* __restrict__ h1)
{
    __shared__ __align__(16) char lds[16384];
    if (blockIdx.y < 12) {
        gemm_body<0, 0, 1>(lds, xb, 768, aWb, 768, ab, 768, nullptr, 0,
                           nullptr, adF, nullptr, x, 12,
                           blockIdx.x * 64, blockIdx.y * 64);
    } else {
        gemm_body<1, 0, 0>(lds, xb, 768, Wd0b, 768, bd0, 384, h1, 384,
                           nullptr, nullptr, nullptr, nullptr, 12,
                           blockIdx.x * 64, (blockIdx.y - 12) * 64);
    }
}

// ---------------------------------------------------------------------------
// L1 head v4: part[z][b][p] = sum_{d in chunk z} -|feat[b][d] - protos[p][d]|
// (f16 in, f32 acc). Grid (16 row-blocks, 4 proto-blocks, 12 d-chunks).
// Block: 128 rows x 64 protos x 64 d. Thread: 8 rows (tr+16i) x 4 protos.
// Inner: packed-f16 sub + bitwise abs + v_dot2_f32_f16 (3 VALU per 2 d/cell).
// Output: NON-ATOMIC coalesced float4 stores into part (atomics were the
// R4 bottleneck: 78.6 MB coherent-atomic traffic = ~70 us serialization).
// ---------------------------------------------------------------------------
__global__ __launch_bounds__(256) void l1_kernel(
    const _Float16* __restrict__ feat, const _Float16* __restrict__ protos,
    float* __restrict__ part)
{
    __shared__ _Float16 fs[128][64];
    __shared__ hf2 pt[32][64];        // [d-pair][proto]
    const int tid = threadIdx.x;
    const int tp = tid & 15, tr = tid >> 4;
    const int rb = blockIdx.x * 128;
    const int pb = blockIdx.y * 64;
    const int db = blockIdx.z * 64;

    // stage fs: thread -> (row r0+32k, granule g), 4 x b128, coalesced
    {
        const int g = tid & 7, r0 = tid >> 3;
#pragma unroll
        for (int k = 0; k < 4; ++k) {
            const int r = r0 + 32 * k;
            *(hf8*)&fs[r][g * 8] =
                *(const hf8*)&feat[(size_t)(rb + r) * 768 + db + g * 8];
        }
    }
    // stage pt (transposed pairs): thread owns proto sp, d-pairs q*8..q*8+7
    {
        const int sp = tid & 63, q = tid >> 6;
        const _Float16* src = &protos[(size_t)(pb + sp) * 768 + db + q * 16];
        hf8 v0 = *(const hf8*)src;
        hf8 v1 = *(const hf8*)(src + 8);
        hf2x4 w0 = __builtin_bit_cast(hf2x4, v0);
        hf2x4 w1 = __builtin_bit_cast(hf2x4, v1);
#pragma unroll
        for (int e = 0; e < 4; ++e)
            pt[q * 8 + e][sp] = w0.v[e];
#pragma unroll
        for (int e = 0; e < 4; ++e)
            pt[q * 8 + 4 + e][sp] = w1.v[e];
    }
    __syncthreads();

    float acc[8][4];
#pragma unroll
    for (int i = 0; i < 8; ++i)
#pragma unroll
        for (int j = 0; j < 4; ++j) acc[i][j] = 0.f;

    const hf2 one2 = {(_Float16)1.0f, (_Float16)1.0f};
#pragma unroll 2
    for (int g = 0; g < 8; ++g) {
        hf2x4 F2[8];
#pragma unroll
        for (int i = 0; i < 8; ++i)
            F2[i] = __builtin_bit_cast(hf2x4,
                        *(const hf8*)&fs[tr + 16 * i][g * 8]);
        hf2x4 P2[4];
#pragma unroll
        for (int q = 0; q < 4; ++q)
            P2[q] = __builtin_bit_cast(hf2x4,
                        *(const hf8*)&pt[g * 4 + q][tp * 4]);
#pragma unroll
        for (int q = 0; q < 4; ++q) {
#pragma unroll
            for (int j = 0; j < 4; ++j) {
                const hf2 pj = P2[q].v[j];
#pragma unroll
                for (int i = 0; i < 8; ++i) {
                    hf2 d = F2[i].v[q] - pj;
                    unsigned ud = __builtin_bit_cast(unsigned, d) & 0x7FFF7FFFu;
                    acc[i][j] = FDOT2(__builtin_bit_cast(hf2, ud), one2, acc[i][j]);
                }
            }
        }
    }
    // coalesced partial store: p = pb + tp*4 (mult of 4; p<200 => p+3<200)
    const int p = pb + tp * 4;
    if (p < 200) {
        const size_t zb = (size_t)blockIdx.z * 2048;
#pragma unroll
        for (int i = 0; i < 8; ++i) {
            float4 v = {-acc[i][0], -acc[i][1], -acc[i][2], -acc[i][3]};
            *(float4*)&part[(zb + rb + tr + 16 * i) * 200 + p] = v;
        }
    }
}

// out[row][p] = sum_z part[z][row][p]; one block per row, thread = p
__global__ __launch_bounds__(256) void l1_reduce(
    const float* __restrict__ part, float* __restrict__ out)
{
    const int row = blockIdx.x;
    const int p = threadIdx.x;
    if (p < 200) {
        float s = 0.f;
#pragma unroll
        for (int z = 0; z < 12; ++z)
            s += part[((size_t)z * 2048 + row) * 200 + p];
        out[(size_t)row * 200 + p] = s;
    }
}

// ---------------------------------------------------------------------------
// Workspace layout (bytes). Total ~23.2 MB.
// PART (19.66 MB) aliases the GEMM-era scratch (xb..adF, all dead when l1
// runs). featH/proH live above PART.
// ---------------------------------------------------------------------------
static constexpr size_t OFF_PART  = 0;          // 12 x 2048 x 200 f32 partials
static constexpr size_t OFF_XB    = 0;          // 2048x768 bf16 (dead before l1)
static constexpr size_t OFF_AWB   = 3145728;    // 768x768 bf16
static constexpr size_t OFF_WD0   = 4325376;    // 384x768
static constexpr size_t OFF_WD1   = 4915200;    // 192x384
static constexpr size_t OFF_WD2   = 5062656;    // 128x192
static constexpr size_t OFF_WD3   = 5111808;    // 64x128
static constexpr size_t OFF_WU0   = 5128192;    // 128x64
static constexpr size_t OFF_WU1   = 5144576;    // 192x128
static constexpr size_t OFF_WU2   = 5193728;    // 384x192
static constexpr size_t OFF_WU3   = 5341184;    // 768x384
static constexpr size_t OFF_H1    = 5931008;    // 2048x384 bf16
static constexpr size_t OFF_H2    = 7503872;    // 2048x192
static constexpr size_t OFF_H3    = 8290304;    // 2048x128
static constexpr size_t OFF_H4    = 8814592;    // 2048x64
static constexpr size_t OFF_U0    = 9076736;    // 2048x128
static constexpr size_t OFF_U1    = 9601024;    // 2048x192
static constexpr size_t OFF_U2    = 10387456;   // 2048x384
static constexpr size_t OFF_ADF   = 11960320;   // 2048x768 f32 (dead before l1)
static constexpr size_t OFF_FEATH = 19660800;   // 2048x768 f16: features
static constexpr size_t OFF_PROH  = 22806528;   // 256x768 f16: protos (padded)

extern "C" void kernel_launch(void* const* d_in, const int* in_sizes, int n_in,
                              void* d_out, int out_size, void* d_ws, size_t ws_size,
                              hipStream_t stream) {
    const float* x      = (const float*)d_in[0];
    const float* aW     = (const float*)d_in[1];
    const float* ab     = (const float*)d_in[2];
    const float* protos = (const float*)d_in[3];
    const float* Wd[4]  = {(const float*)d_in[4], (const float*)d_in[6],
                           (const float*)d_in[8], (const float*)d_in[10]};
    const float* bd[4]  = {(const float*)d_in[5], (const float*)d_in[7],
                           (const float*)d_in[9], (const float*)d_in[11]};
    const float* Wu[4]  = {(const float*)d_in[12], (const float*)d_in[14],
                           (const float*)d_in[16], (const float*)d_in[18]};
    const float* bu[4]  = {(const float*)d_in[13], (const float*)d_in[15],
                           (const float*)d_in[17], (const float*)d_in[19]};
    float* out = (float*)d_out;
    char* ws = (char*)d_ws;

    u16* xb    = (u16*)(ws + OFF_XB);
    u16* aWb   = (u16*)(ws + OFF_AWB);
    u16* Wd0b  = (u16*)(ws + OFF_WD0);
    u16* Wd1b  = (u16*)(ws + OFF_WD1);
    u16* Wd2b  = (u16*)(ws + OFF_WD2);
    u16* Wd3b  = (u16*)(ws + OFF_WD3);
    u16* Wu0b  = (u16*)(ws + OFF_WU0);
    u16* Wu1b  = (u16*)(ws + OFF_WU1);
    u16* Wu2b  = (u16*)(ws + OFF_WU2);
    u16* Wu3b  = (u16*)(ws + OFF_WU3);
    u16* h1    = (u16*)(ws + OFF_H1);
    u16* h2    = (u16*)(ws + OFF_H2);
    u16* h3    = (u16*)(ws + OFF_H3);
    u16* h4    = (u16*)(ws + OFF_H4);
    u16* u0    = (u16*)(ws + OFF_U0);
    u16* u1    = (u16*)(ws + OFF_U1);
    u16* u2    = (u16*)(ws + OFF_U2);
    float* adF = (float*)(ws + OFF_ADF);
    float* part = (float*)(ws + OFF_PART);
    _Float16* featH = (_Float16*)(ws + OFF_FEATH);
    _Float16* proH  = (_Float16*)(ws + OFF_PROH);

    // --- 1. convert/pad everything (bf16 for GEMM, f16 for L1) ---
    CvtTab tab;
    int blk = 0;
    auto set = [&](int i, const float* s, u16* d, int N, int K, int Np, int Kp,
                   int fmt) {
        tab.t[i] = {s, d, N, K, Np, Kp, blk, fmt};
        blk += (Np * Kp + 255) / 256;
    };
    set(0,  x,      xb,          2048, 768, 2048, 768, 0);
    set(1,  aW,     aWb,         768,  768, 768,  768, 0);
    set(2,  Wd[0],  Wd0b,        384,  768, 384,  768, 0);
    set(3,  Wd[1],  Wd1b,        192,  384, 192,  384, 0);
    set(4,  Wd[2],  Wd2b,        96,   192, 128,  192, 0);
    set(5,  Wd[3],  Wd3b,        48,   96,  64,   128, 0);
    set(6,  Wu[0],  Wu0b,        96,   48,  128,  64,  0);
    set(7,  Wu[1],  Wu1b,        192,  96,  192,  128, 0);
    set(8,  Wu[2],  Wu2b,        384,  192, 384,  192, 0);
    set(9,  Wu[3],  Wu3b,        768,  384, 768,  384, 0);
    set(10, protos, (u16*)proH,  200,  768, 256,  768, 1);
    cvt_all<<<blk, 256, 0, stream>>>(tab);

    // --- 2. GEMM chain ---
    // adapter (adF = x + x@aW.T + ab) merged with down0 (h1) — both read xb
    gemm_ad0<<<dim3(32, 18), 256, 0, stream>>>(xb, aWb, ab, adF, x, Wd0b, bd[0], h1);
    gemm_k<1,0,0><<<dim3(32,3), 256, 0, stream>>>(h1, 384, Wd1b, 384, bd[1], 192,
        h2, 192, nullptr, nullptr, nullptr, nullptr, 6);
    gemm_k<1,0,0><<<dim3(32,2), 256, 0, stream>>>(h2, 192, Wd2b, 192, bd[2], 96,
        h3, 128, nullptr, nullptr, nullptr, nullptr, 3);
    gemm_k<1,0,0><<<dim3(32,1), 256, 0, stream>>>(h3, 128, Wd3b, 128, bd[3], 48,
        h4, 64, nullptr, nullptr, nullptr, nullptr, 2);
    gemm_k<1,1,0><<<dim3(32,2), 256, 0, stream>>>(h4, 64, Wu0b, 64, bu[0], 96,
        u0, 128, h3, nullptr, nullptr, nullptr, 1);     // u0 = relu(.)+h3
    gemm_k<1,1,0><<<dim3(32,3), 256, 0, stream>>>(u0, 128, Wu1b, 128, bu[1], 192,
        u1, 192, h2, nullptr, nullptr, nullptr, 2);     // u1 = relu(.)+h2
    gemm_k<1,0,0><<<dim3(32,6), 256, 0, stream>>>(u1, 192, Wu2b, 192, bu[2], 384,
        u2, 384, nullptr, nullptr, nullptr, nullptr, 3);
    // u3: featH = (f16)(relu(u2@Wu3.T + bu3) + adF)
    gemm_k<1,0,2><<<dim3(32,12), 256, 0, stream>>>(u2, 384, Wu3b, 384, bu[3], 768,
        nullptr, 0, nullptr, nullptr, featH, adF, 6);

    // --- 3. L1 prototype head: partials (no atomics), then reduce ---
    l1_kernel<<<dim3(16, 4, 12), 256, 0, stream>>>(featH, proH, part);
    l1_reduce<<<dim3(2048), 256, 0, stream>>>(part, out);
}

// Round 6
// 84.183 us; speedup vs baseline: 1.6501x; 1.0759x over previous
//
#include <hip/hip_runtime.h>

typedef __attribute__((ext_vector_type(8))) __bf16 bf16x8;
typedef __attribute__((ext_vector_type(4))) float f32x4;
typedef _Float16 hf2 __attribute__((ext_vector_type(2)));
typedef _Float16 hf8 __attribute__((ext_vector_type(8)));
typedef unsigned short u16;
typedef struct { hf2 v[4]; } hf2x4;   // register-friendly view of hf8

__device__ __forceinline__ float bf2f(u16 h) {
    return __uint_as_float(((unsigned int)h) << 16);
}
__device__ __forceinline__ u16 f2bf(float f) {
    unsigned int u = __float_as_uint(f);
    u += 0x7fffu + ((u >> 16) & 1u);   // RNE
    return (u16)(u >> 16);
}

#if __has_builtin(__builtin_amdgcn_fdot2)
__device__ __forceinline__ float FDOT2(hf2 a, hf2 b, float c) {
    return __builtin_amdgcn_fdot2(a, b, c, false);
}
#else
__device__ __forceinline__ float FDOT2(hf2 a, hf2 b, float c) {
    return c + (float)a[0] + (float)a[1];   // b is all-ones in our use
}
#endif

#define GLOAD_LDS16(gsrc, ldst)                                                          \
    __builtin_amdgcn_global_load_lds(                                                    \
        (__attribute__((address_space(1))) unsigned int*)(gsrc),                         \
        (__attribute__((address_space(3))) unsigned int*)(ldst), 16, 0, 0)

// ---------------------------------------------------------------------------
// Fused f32 -> bf16/f16 convert with zero-padding to (Npad, Kpad)
// ---------------------------------------------------------------------------
struct CvtDesc { const float* src; u16* dst; int N, K, Npad, Kpad, blk0, fmt; };
struct CvtTab { CvtDesc t[11]; };

__global__ __launch_bounds__(256) void cvt_all(CvtTab tab) {
    int b = blockIdx.x;
    int ti = 0;
#pragma unroll
    for (int j = 1; j < 11; ++j)
        if (b >= tab.t[j].blk0) ti = j;
    const CvtDesc c = tab.t[ti];
    long i = (long)(b - c.blk0) * 256 + threadIdx.x;
    long tot = (long)c.Npad * c.Kpad;
    if (i >= tot) return;
    int n = (int)(i / c.Kpad);
    int k = (int)(i - (long)n * c.Kpad);
    float v = (n < c.N && k < c.K) ? c.src[(long)n * c.K + k] : 0.f;
    if (c.fmt) {
        _Float16 h = (_Float16)v;
        c.dst[i] = __builtin_bit_cast(u16, h);
    } else {
        c.dst[i] = f2bf(v);
    }
}

// ---------------------------------------------------------------------------
// bf16 MFMA GEMM body: out[m][n] = epi( sum_k A[m][k]*W[n][k] + bias[n] )
// BM=BN=BK=64, 256 threads (4 waves as 2x2), 16x16x32 MFMA.
// LDS tiles [64][64] bf16, XOR-swizzled granules via pre-swizzled global
// source + linear global_load_lds dest (rule 21).
// MODE: 0 = bf16 out (+opt res add), 1 = f32 out + addF, 2 = f16 out + addF
// ---------------------------------------------------------------------------
template<int RELU, int HASRES, int MODE>
__device__ __forceinline__ void gemm_body(
    char* lds,
    const u16* __restrict__ A, int lda,
    const u16* __restrict__ W, int ldw,
    const float* __restrict__ bias, int Nreal,
    u16* __restrict__ outB, int ldo,
    const u16* __restrict__ res,
    float* __restrict__ outF, _Float16* __restrict__ outH,
    const float* __restrict__ addF,
    int nk, int mb, int nb)
{
    char* ldsA = lds;
    char* ldsB = lds + 8192;

    const int tid  = threadIdx.x;
    const int wave = tid >> 6;
    const int lane = tid & 63;
    const int wr = wave >> 1, wc = wave & 1;
    const int lr = lane & 15, lk = lane >> 4;

    f32x4 acc[2][2];
#pragma unroll
    for (int i = 0; i < 2; ++i)
#pragma unroll
        for (int j = 0; j < 2; ++j)
#pragma unroll
            for (int e = 0; e < 4; ++e) acc[i][j][e] = 0.f;

    // staging granule geometry (8KB tile = 512 granules of 16B; 2 per thread)
    const int g0 = wave * 64 + lane;
    const int r0 = g0 >> 3, l0 = (g0 & 7) ^ (r0 & 7);
    const int g1 = g0 + 256;
    const int r1 = g1 >> 3, l1 = (g1 & 7) ^ (r1 & 7);

    for (int kt = 0; kt < nk; ++kt) {
        const int kk = kt * 64;
        GLOAD_LDS16(A + (size_t)(mb + r0) * lda + kk + l0 * 8, ldsA + wave * 1024);
        GLOAD_LDS16(A + (size_t)(mb + r1) * lda + kk + l1 * 8, ldsA + 4096 + wave * 1024);
        GLOAD_LDS16(W + (size_t)(nb + r0) * ldw + kk + l0 * 8, ldsB + wave * 1024);
        GLOAD_LDS16(W + (size_t)(nb + r1) * ldw + kk + l1 * 8, ldsB + 4096 + wave * 1024);
        __syncthreads();   // compiler drains vmcnt(0) before barrier
#pragma unroll
        for (int ks = 0; ks < 2; ++ks) {
            bf16x8 af[2], bfr[2];
#pragma unroll
            for (int mi = 0; mi < 2; ++mi) {
                int m_loc = wr * 32 + mi * 16 + lr;
                int gr = (ks * 4 + lk) ^ (m_loc & 7);
                af[mi] = *(const bf16x8*)(ldsA + m_loc * 128 + gr * 16);
            }
#pragma unroll
            for (int ni = 0; ni < 2; ++ni) {
                int n_loc = wc * 32 + ni * 16 + lr;
                int gr = (ks * 4 + lk) ^ (n_loc & 7);
                bfr[ni] = *(const bf16x8*)(ldsB + n_loc * 128 + gr * 16);
            }
#pragma unroll
            for (int mi = 0; mi < 2; ++mi)
#pragma unroll
                for (int ni = 0; ni < 2; ++ni)
                    acc[mi][ni] = __builtin_amdgcn_mfma_f32_16x16x32_bf16(
                        af[mi], bfr[ni], acc[mi][ni], 0, 0, 0);
        }
        __syncthreads();
    }

    // epilogue: C/D layout col = lane&15, row = (lane>>4)*4 + reg (m89-verified)
#pragma unroll
    for (int mi = 0; mi < 2; ++mi) {
#pragma unroll
        for (int ni = 0; ni < 2; ++ni) {
            const int n_g = nb + wc * 32 + ni * 16 + lr;
            const float bv = (n_g < Nreal) ? bias[n_g] : 0.f;
#pragma unroll
            for (int r = 0; r < 4; ++r) {
                const int m_g = mb + wr * 32 + mi * 16 + lk * 4 + r;
                float v = acc[mi][ni][r] + bv;
                if (RELU) v = fmaxf(v, 0.f);
                if (HASRES) v += bf2f(res[(size_t)m_g * ldo + n_g]);
                if (MODE == 1) {
                    outF[(size_t)m_g * 768 + n_g] = v + addF[(size_t)m_g * 768 + n_g];
                } else if (MODE == 2) {
                    outH[(size_t)m_g * 768 + n_g] =
                        (_Float16)(v + addF[(size_t)m_g * 768 + n_g]);
                } else {
                    outB[(size_t)m_g * ldo + n_g] = f2bf(v);
                }
            }
        }
    }
}

template<int RELU, int HASRES, int MODE>
__global__ __launch_bounds__(256) void gemm_k(
    const u16* __restrict__ A, int lda,
    const u16* __restrict__ W, int ldw,
    const float* __restrict__ bias, int Nreal,
    u16* __restrict__ outB, int ldo,
    const u16* __restrict__ res,
    float* __restrict__ outF, _Float16* __restrict__ outH,
    const float* __restrict__ addF, int nk)
{
    __shared__ __align__(16) char lds[16384];
    gemm_body<RELU, HASRES, MODE>(lds, A, lda, W, ldw, bias, Nreal, outB, ldo,
                                  res, outF, outH, addF, nk,
                                  blockIdx.x * 64, blockIdx.y * 64);
}

// merged adapter (MODE 1, f32 out = v + x) and down0 (bf16 relu out): share A=xb
__global__ __launch_bounds__(256) void gemm_ad0(
    const u16* __restrict__ xb,
    const u16* __restrict__ aWb, const float* __restrict__ ab,
    float* __restrict__ adF, const float* __restrict__ x,
    const u16* __restrict__ Wd0b, const float* __restrict__ bd0,
    u16* __restrict__ h1)
{
    __shared__ __align__(16) char lds[16384];
    if (blockIdx.y < 12) {
        gemm_body<0, 0, 1>(lds, xb, 768, aWb, 768, ab, 768, nullptr, 0,
                           nullptr, adF, nullptr, x, 12,
                           blockIdx.x * 64, blockIdx.y * 64);
    } else {
        gemm_body<1, 0, 0>(lds, xb, 768, Wd0b, 768, bd0, 384, h1, 384,
                           nullptr, nullptr, nullptr, nullptr, 12,
                           blockIdx.x * 64, (blockIdx.y - 12) * 64);
    }
}

// ---------------------------------------------------------------------------
// Fused middle chain: d1 -> d2 -> d3 -> u0(+h3) -> u1(+h2) -> u2, one launch.
// Grid 128 blocks x 16 rows, 256 thr (4 waves). Activations live in LDS
// (residuals never touch HBM); weights are L2-resident and read directly
// from global as MFMA B-fragments (no LDS staging).
// Fragment layouts identical to gemm_body (A: lane(lr,lk) -> A[lr][lk*8..];
// C/D: col=lr, row=lk*4+r). All LDS leading dims = 4 banks mod 32.
// ---------------------------------------------------------------------------
template<int K, int NPAD, int NREAL, int RES, int OUTG>
__device__ __forceinline__ void layer16(
    const u16* __restrict__ W, int ldw, const float* __restrict__ bias,
    const u16* actIn, int ldin,
    u16* actOut, int ldout,
    const u16* resid, int ldres,
    u16* __restrict__ gout, int ldg)
{
    constexpr int TPW = NPAD / 64;     // 16-wide N-tiles per wave (4 waves)
    const int tid = threadIdx.x;
    const int wave = tid >> 6, lane = tid & 63;
    const int lr = lane & 15, lk = lane >> 4;

    f32x4 acc[TPW];
#pragma unroll
    for (int t = 0; t < TPW; ++t)
#pragma unroll
        for (int e = 0; e < 4; ++e) acc[t][e] = 0.f;

#pragma unroll
    for (int kk = 0; kk < K / 32; ++kk) {
        const bf16x8 a = *(const bf16x8*)&actIn[lr * ldin + kk * 32 + lk * 8];
#pragma unroll
        for (int t = 0; t < TPW; ++t) {
            const int nc = (wave * TPW + t) * 16 + lr;
            const bf16x8 b = *(const bf16x8*)&W[(size_t)nc * ldw + kk * 32 + lk * 8];
            acc[t] = __builtin_amdgcn_mfma_f32_16x16x32_bf16(a, b, acc[t], 0, 0, 0);
        }
    }
#pragma unroll
    for (int t = 0; t < TPW; ++t) {
        const int nc = (wave * TPW + t) * 16 + lr;
        const float bv = (nc < NREAL) ? bias[nc] : 0.f;
#pragma unroll
        for (int r = 0; r < 4; ++r) {
            const int row = lk * 4 + r;
            float v = fmaxf(acc[t][r] + bv, 0.f);
            if (RES) v += bf2f(resid[row * ldres + nc]);
            const u16 o = f2bf(v);
            if (OUTG) gout[(size_t)row * ldg + nc] = o;
            else      actOut[row * ldout + nc] = o;
        }
    }
}

__global__ __launch_bounds__(256) void chain_mid(
    const u16* __restrict__ h1,
    const u16* __restrict__ Wd1b, const float* __restrict__ bd1,
    const u16* __restrict__ Wd2b, const float* __restrict__ bd2,
    const u16* __restrict__ Wd3b, const float* __restrict__ bd3,
    const u16* __restrict__ Wu0b, const float* __restrict__ bu0,
    const u16* __restrict__ Wu1b, const float* __restrict__ bu1,
    const u16* __restrict__ Wu2b, const float* __restrict__ bu2,
    u16* __restrict__ u2)
{
    __shared__ u16 A[16 * 392];   // h1 in; later E=[0..16*136) u0out, F=[16*136..16*136+16*200) u1out
    __shared__ u16 B[16 * 200];   // h2 skip (192w)
    __shared__ u16 C[16 * 136];   // h3 skip (128w, cols 96.. = 0)
    __shared__ u16 D[16 * 72];    // h4 (64w, cols 48.. = 0)
    const int tid = threadIdx.x;
    const int rb = blockIdx.x * 16;

    // stage h1: 16 rows x 48 granules of 8 bf16, coalesced b128
    for (int i = tid; i < 768; i += 256) {
        const int r = i / 48, c = i - r * 48;
        *(bf16x8*)&A[r * 392 + c * 8] =
            *(const bf16x8*)&h1[(size_t)(rb + r) * 384 + c * 8];
    }
    __syncthreads();
    layer16<384, 192, 192, 0, 0>(Wd1b, 384, bd1, A, 392, B, 200, nullptr, 0, nullptr, 0);
    __syncthreads();
    layer16<192, 128,  96, 0, 0>(Wd2b, 192, bd2, B, 200, C, 136, nullptr, 0, nullptr, 0);
    __syncthreads();
    layer16<128,  64,  48, 0, 0>(Wd3b, 128, bd3, C, 136, D,  72, nullptr, 0, nullptr, 0);
    __syncthreads();
    u16* E = A;                 // 16 x 136
    u16* F = A + 16 * 136;      // 16 x 200
    layer16< 64, 128,  96, 1, 0>(Wu0b,  64, bu0, D,  72, E, 136, C, 136, nullptr, 0);
    __syncthreads();
    layer16<128, 192, 192, 1, 0>(Wu1b, 128, bu1, E, 136, F, 200, B, 200, nullptr, 0);
    __syncthreads();
    layer16<192, 384, 384, 0, 1>(Wu2b, 192, bu2, F, 200, nullptr, 0, nullptr, 0,
                                 u2 + (size_t)rb * 384, 384);
}

// ---------------------------------------------------------------------------
// L1 head v4: part[z][b][p] = sum_{d in chunk z} -|feat[b][d] - protos[p][d]|
// (f16 in, f32 acc). Grid (16 row-blocks, 4 proto-blocks, 12 d-chunks).
// Block: 128 rows x 64 protos x 64 d. Thread: 8 rows (tr+16i) x 4 protos.
// Inner: packed-f16 sub + bitwise abs + v_dot2_f32_f16 (3 VALU per 2 d/cell).
// Output: NON-ATOMIC coalesced float4 stores into part (atomics were the
// R4 bottleneck: 78.6 MB coherent-atomic traffic = ~70 us serialization).
// ---------------------------------------------------------------------------
__global__ __launch_bounds__(256) void l1_kernel(
    const _Float16* __restrict__ feat, const _Float16* __restrict__ protos,
    float* __restrict__ part)
{
    __shared__ _Float16 fs[128][64];
    __shared__ hf2 pt[32][64];        // [d-pair][proto]
    const int tid = threadIdx.x;
    const int tp = tid & 15, tr = tid >> 4;
    const int rb = blockIdx.x * 128;
    const int pb = blockIdx.y * 64;
    const int db = blockIdx.z * 64;

    // stage fs: thread -> (row r0+32k, granule g), 4 x b128, coalesced
    {
        const int g = tid & 7, r0 = tid >> 3;
#pragma unroll
        for (int k = 0; k < 4; ++k) {
            const int r = r0 + 32 * k;
            *(hf8*)&fs[r][g * 8] =
                *(const hf8*)&feat[(size_t)(rb + r) * 768 + db + g * 8];
        }
    }
    // stage pt (transposed pairs): thread owns proto sp, d-pairs q*8..q*8+7
    {
        const int sp = tid & 63, q = tid >> 6;
        const _Float16* src = &protos[(size_t)(pb + sp) * 768 + db + q * 16];
        hf8 v0 = *(const hf8*)src;
        hf8 v1 = *(const hf8*)(src + 8);
        hf2x4 w0 = __builtin_bit_cast(hf2x4, v0);
        hf2x4 w1 = __builtin_bit_cast(hf2x4, v1);
#pragma unroll
        for (int e = 0; e < 4; ++e)
            pt[q * 8 + e][sp] = w0.v[e];
#pragma unroll
        for (int e = 0; e < 4; ++e)
            pt[q * 8 + 4 + e][sp] = w1.v[e];
    }
    __syncthreads();

    float acc[8][4];
#pragma unroll
    for (int i = 0; i < 8; ++i)
#pragma unroll
        for (int j = 0; j < 4; ++j) acc[i][j] = 0.f;

    const hf2 one2 = {(_Float16)1.0f, (_Float16)1.0f};
#pragma unroll 2
    for (int g = 0; g < 8; ++g) {
        hf2x4 F2[8];
#pragma unroll
        for (int i = 0; i < 8; ++i)
            F2[i] = __builtin_bit_cast(hf2x4,
                        *(const hf8*)&fs[tr + 16 * i][g * 8]);
        hf2x4 P2[4];
#pragma unroll
        for (int q = 0; q < 4; ++q)
            P2[q] = __builtin_bit_cast(hf2x4,
                        *(const hf8*)&pt[g * 4 + q][tp * 4]);
#pragma unroll
        for (int q = 0; q < 4; ++q) {
#pragma unroll
            for (int j = 0; j < 4; ++j) {
                const hf2 pj = P2[q].v[j];
#pragma unroll
                for (int i = 0; i < 8; ++i) {
                    hf2 d = F2[i].v[q] - pj;
                    unsigned ud = __builtin_bit_cast(unsigned, d) & 0x7FFF7FFFu;
                    acc[i][j] = FDOT2(__builtin_bit_cast(hf2, ud), one2, acc[i][j]);
                }
            }
        }
    }
    // coalesced partial store: p = pb + tp*4 (mult of 4; p<200 => p+3<200)
    const int p = pb + tp * 4;
    if (p < 200) {
        const size_t zb = (size_t)blockIdx.z * 2048;
#pragma unroll
        for (int i = 0; i < 8; ++i) {
            float4 v = {-acc[i][0], -acc[i][1], -acc[i][2], -acc[i][3]};
            *(float4*)&part[(zb + rb + tr + 16 * i) * 200 + p] = v;
        }
    }
}

// out[row][p] = sum_z part[z][row][p]; one block per row, thread = p
__global__ __launch_bounds__(256) void l1_reduce(
    const float* __restrict__ part, float* __restrict__ out)
{
    const int row = blockIdx.x;
    const int p = threadIdx.x;
    if (p < 200) {
        float s = 0.f;
#pragma unroll
        for (int z = 0; z < 12; ++z)
            s += part[((size_t)z * 2048 + row) * 200 + p];
        out[(size_t)row * 200 + p] = s;
    }
}

// ---------------------------------------------------------------------------
// Workspace layout (bytes). Total ~23.2 MB.
// PART (19.66 MB) aliases the GEMM-era scratch (xb..adF, all dead when l1
// runs). featH/proH live above PART.
// ---------------------------------------------------------------------------
static constexpr size_t OFF_PART  = 0;          // 12 x 2048 x 200 f32 partials
static constexpr size_t OFF_XB    = 0;          // 2048x768 bf16 (dead before l1)
static constexpr size_t OFF_AWB   = 3145728;    // 768x768 bf16
static constexpr size_t OFF_WD0   = 4325376;    // 384x768
static constexpr size_t OFF_WD1   = 4915200;    // 192x384
static constexpr size_t OFF_WD2   = 5062656;    // 128x192
static constexpr size_t OFF_WD3   = 5111808;    // 64x128
static constexpr size_t OFF_WU0   = 5128192;    // 128x64
static constexpr size_t OFF_WU1   = 5144576;    // 192x128
static constexpr size_t OFF_WU2   = 5193728;    // 384x192
static constexpr size_t OFF_WU3   = 5341184;    // 768x384
static constexpr size_t OFF_H1    = 5931008;    // 2048x384 bf16
static constexpr size_t OFF_U2    = 10387456;   // 2048x384 bf16
static constexpr size_t OFF_ADF   = 11960320;   // 2048x768 f32 (dead before l1)
static constexpr size_t OFF_FEATH = 19660800;   // 2048x768 f16: features
static constexpr size_t OFF_PROH  = 22806528;   // 256x768 f16: protos (padded)

extern "C" void kernel_launch(void* const* d_in, const int* in_sizes, int n_in,
                              void* d_out, int out_size, void* d_ws, size_t ws_size,
                              hipStream_t stream) {
    const float* x      = (const float*)d_in[0];
    const float* aW     = (const float*)d_in[1];
    const float* ab     = (const float*)d_in[2];
    const float* protos = (const float*)d_in[3];
    const float* Wd[4]  = {(const float*)d_in[4], (const float*)d_in[6],
                           (const float*)d_in[8], (const float*)d_in[10]};
    const float* bd[4]  = {(const float*)d_in[5], (const float*)d_in[7],
                           (const float*)d_in[9], (const float*)d_in[11]};
    const float* Wu[4]  = {(const float*)d_in[12], (const float*)d_in[14],
                           (const float*)d_in[16], (const float*)d_in[18]};
    const float* bu[4]  = {(const float*)d_in[13], (const float*)d_in[15],
                           (const float*)d_in[17], (const float*)d_in[19]};
    float* out = (float*)d_out;
    char* ws = (char*)d_ws;

    u16* xb    = (u16*)(ws + OFF_XB);
    u16* aWb   = (u16*)(ws + OFF_AWB);
    u16* Wd0b  = (u16*)(ws + OFF_WD0);
    u16* Wd1b  = (u16*)(ws + OFF_WD1);
    u16* Wd2b  = (u16*)(ws + OFF_WD2);
    u16* Wd3b  = (u16*)(ws + OFF_WD3);
    u16* Wu0b  = (u16*)(ws + OFF_WU0);
    u16* Wu1b  = (u16*)(ws + OFF_WU1);
    u16* Wu2b  = (u16*)(ws + OFF_WU2);
    u16* Wu3b  = (u16*)(ws + OFF_WU3);
    u16* h1    = (u16*)(ws + OFF_H1);
    u16* u2    = (u16*)(ws + OFF_U2);
    float* adF = (float*)(ws + OFF_ADF);
    float* part = (float*)(ws + OFF_PART);
    _Float16* featH = (_Float16*)(ws + OFF_FEATH);
    _Float16* proH  = (_Float16*)(ws + OFF_PROH);

    // --- 1. convert/pad everything (bf16 for GEMM, f16 for L1) ---
    CvtTab tab;
    int blk = 0;
    auto set = [&](int i, const float* s, u16* d, int N, int K, int Np, int Kp,
                   int fmt) {
        tab.t[i] = {s, d, N, K, Np, Kp, blk, fmt};
        blk += (Np * Kp + 255) / 256;
    };
    set(0,  x,      xb,          2048, 768, 2048, 768, 0);
    set(1,  aW,     aWb,         768,  768, 768,  768, 0);
    set(2,  Wd[0],  Wd0b,        384,  768, 384,  768, 0);
    set(3,  Wd[1],  Wd1b,        192,  384, 192,  384, 0);
    set(4,  Wd[2],  Wd2b,        96,   192, 128,  192, 0);
    set(5,  Wd[3],  Wd3b,        48,   96,  64,   128, 0);
    set(6,  Wu[0],  Wu0b,        96,   48,  128,  64,  0);
    set(7,  Wu[1],  Wu1b,        192,  96,  192,  128, 0);
    set(8,  Wu[2],  Wu2b,        384,  192, 384,  192, 0);
    set(9,  Wu[3],  Wu3b,        768,  384, 768,  384, 0);
    set(10, protos, (u16*)proH,  200,  768, 256,  768, 1);
    cvt_all<<<blk, 256, 0, stream>>>(tab);

    // --- 2. GEMM chain ---
    // adapter (adF = x + x@aW.T + ab) merged with down0 (h1) — both read xb
    gemm_ad0<<<dim3(32, 18), 256, 0, stream>>>(xb, aWb, ab, adF, x, Wd0b, bd[0], h1);
    // middle chain d1..u2 fused into ONE launch (was 6 underfilled GEMMs)
    chain_mid<<<dim3(128), 256, 0, stream>>>(h1,
        Wd1b, bd[1], Wd2b, bd[2], Wd3b, bd[3],
        Wu0b, bu[0], Wu1b, bu[1], Wu2b, bu[2], u2);
    // u3: featH = (f16)(relu(u2@Wu3.T + bu3) + adF)
    gemm_k<1,0,2><<<dim3(32,12), 256, 0, stream>>>(u2, 384, Wu3b, 384, bu[3], 768,
        nullptr, 0, nullptr, nullptr, featH, adF, 6);

    // --- 3. L1 prototype head: partials (no atomics), then reduce ---
    l1_kernel<<<dim3(16, 4, 12), 256, 0, stream>>>(featH, proH, part);
    l1_reduce<<<dim3(2048), 256, 0, stream>>>(part, out);
}